// Round 11
// baseline (588.548 us; speedup 1.0000x reference)
//
#include <hip/hip_runtime.h>
#include <math.h>

#define Nrows 16384          // B*H*W
#define NE 8192
#define Kdim 256
#define HWsz 1024
#define NSPL 4               // code-group splits (cg)
#define BETAF 0.25f
#define NGATHBLK 1024        // gather grid: 256 row-tiles x 4 c-quarters

typedef __attribute__((ext_vector_type(8))) short bf16x8;
typedef __attribute__((ext_vector_type(16))) float f32x16;
typedef unsigned short u16;

__device__ inline u16 bf16_rne(float x) {
  unsigned int u = __float_as_uint(x);
  return (u16)((u + 0x7FFFu + ((u >> 16) & 1u)) >> 16);
}
__device__ inline float bf16_tof(u16 h) {
  return __uint_as_float(((unsigned int)h) << 16);
}

// ---- cc[j] = sum_k codebook[j][k]^2 (bit-identical to r1-r15) -------------
__global__ __launch_bounds__(256) void cc_kernel(const float* __restrict__ cb,
                                                 float* __restrict__ cc) {
  int wave = threadIdx.x >> 6;
  int lane = threadIdx.x & 63;
  int row = blockIdx.x * 4 + wave;
  const float4 v = *(const float4*)(cb + (size_t)row * Kdim + lane * 4);
  float s = v.x * v.x + v.y * v.y + v.z * v.z + v.w * v.w;
  for (int off = 32; off; off >>= 1) s += __shfl_down(s, off);
  if (lane == 0) cc[row] = s;
}

// ---- codebook -> frag-order bf16 splits Cf (unchanged r4-r15) -------------
// Group (j32, arr, k16) of 512 u16 at ((j32*3+arr)*16 + k16)*512;
// within group: (khalf*32 + j%32)*8 + i.
__global__ __launch_bounds__(256) void conv_cb(const float* __restrict__ cb,
                                               u16* __restrict__ Cf) {
  const int g = blockIdx.x * 256 + threadIdx.x;   // 0 .. 8192*16-1
  const int j = g >> 4, k16 = g & 15;
  const float* src = cb + (size_t)j * Kdim + k16 * 16;
  float f[16];
#pragma unroll
  for (int q = 0; q < 4; ++q) {
    const float4 v = ((const float4*)src)[q];
    f[q * 4 + 0] = v.x; f[q * 4 + 1] = v.y; f[q * 4 + 2] = v.z; f[q * 4 + 3] = v.w;
  }
  u16 h[3][16];
#pragma unroll
  for (int i = 0; i < 16; ++i) {
    const u16 q0 = bf16_rne(f[i]);
    const float r1 = f[i] - bf16_tof(q0);
    const u16 q1 = bf16_rne(r1);
    const float r2 = r1 - bf16_tof(q1);
    h[0][i] = q0; h[1][i] = q1; h[2][i] = bf16_rne(r2);
  }
  const int j32 = j >> 5, li = j & 31;
#pragma unroll
  for (int arr = 0; arr < 3; ++arr) {
#pragma unroll
    for (int kh = 0; kh < 2; ++kh) {
      const size_t off = ((size_t)(j32 * 3 + arr) * 16 + k16) * 512 + (kh * 32 + li) * 8;
      *(int4*)(Cf + off) = *(int4*)&h[arr][kh * 8];
    }
  }
}

// ---- z (B,C,H,W) -> frag-order bf16 splits Zf + zz (unchanged r4-r15) -----
__global__ __launch_bounds__(256) void conv_z(const float* __restrict__ z,
                                              u16* __restrict__ Zf,
                                              float* __restrict__ zz) {
  __shared__ float tile[64][68];
  const int t = threadIdx.x;
  const int bid = blockIdx.x;
  const int n0 = bid * 64;
  const int b = bid >> 4;
  const int hw0 = (bid & 15) << 6;
  const float* zb = z + (size_t)b * (Kdim * HWsz) + hw0;
  float zzacc = 0.f;
  const int rr = t >> 2;
  const int kq = (t & 3) * 16;
  for (int kc = 0; kc < 4; ++kc) {
#pragma unroll
    for (int i = 0; i < 16; ++i) {
      const int idx = i * 256 + t;
      const int k = idx >> 6, r = idx & 63;
      tile[r][k] = zb[(size_t)(kc * 64 + k) * HWsz + r];
    }
    __syncthreads();
    if (t < 64) {
      for (int k = 0; k < 64; ++k) {
        const float a = tile[t][k];
        zzacc = fmaf(a, a, zzacc);
      }
    }
    u16 h[3][16];
#pragma unroll
    for (int i = 0; i < 16; ++i) {
      const float fv = tile[rr][kq + i];
      const u16 q0 = bf16_rne(fv);
      const float r1 = fv - bf16_tof(q0);
      const u16 q1 = bf16_rne(r1);
      const float r2 = r1 - bf16_tof(q1);
      h[0][i] = q0; h[1][i] = q1; h[2][i] = bf16_rne(r2);
    }
    const int k16 = kc * 4 + (t & 3);
    const int n32 = bid * 2 + (rr >> 5), li = rr & 31;
#pragma unroll
    for (int arr = 0; arr < 3; ++arr) {
#pragma unroll
      for (int kh = 0; kh < 2; ++kh) {
        const size_t off = ((size_t)(n32 * 3 + arr) * 16 + k16) * 512 + (kh * 32 + li) * 8;
        *(int4*)(Zf + off) = *(int4*)&h[arr][kh * 8];
      }
    }
    __syncthreads();
  }
  if (t < 64) zz[n0 + t] = zzacc;
}

// ---- main GEMM+argmin (r16): A direct global->VGPR, no LDS staging --------
// r15 showed (a) barrier removal is right but 1-kc phases are latency-bound
// at the vmcnt wait, and (b) FETCH stayed 64 MB: the 4 waves' duplicate A
// loads are L1/L2-absorbed (A is wave-independent; only B differs). Then
// the entire gll16->LDS->ds_read round trip buys nothing — load A fragments
// DIRECTLY into registers: per lane 16 B contiguous (coalesced dwordx4).
// Inner loop = 6 reg-loads (next kc, ping-pong bank) + 12 MFMAs; zero LDS
// ops, zero barriers, zero inline asm — compiler auto-emits counted
// vmcnt(6) for this pure-register pipeline (AITER's 1:1 interleave shape).
// Banks statically indexed via full unroll (rule #20). Prefetch dist 1:
// ~194 cyc MFMA cover vs ~50-200 cyc L1/L2 hit. MFMA order per acc element
// unchanged -> bit-identical to r3-r15. LDS = 8 KB ccs only.
__global__ __launch_bounds__(256, 2) void vq_gemm(
    const u16* __restrict__ Cf, const u16* __restrict__ Zf,
    const float* __restrict__ cc, const float* __restrict__ zz,
    float* __restrict__ pd, int* __restrict__ pj) {
  __shared__ float ccs[2048];

  const int t = threadIdx.x;
  const int lane = t & 63;
  const int w = __builtin_amdgcn_readfirstlane(t >> 6);   // 0..3
  const int bid = blockIdx.x;
  const int cg = bid & 3;          // code slice (2048 codes), XCD-pinned
  const int rt = bid >> 2;         // row tile (128 rows)
  const int n32 = rt * 4 + w;      // this wave's 32-row group

#pragma unroll
  for (int i = 0; i < 8; ++i) ccs[i * 256 + t] = cc[cg * 2048 + i * 256 + t];

  const float zzv = zz[n32 * 32 + (lane & 31)];

  // B (z-rows) persistent: 16 kc x 3 limbs x bf16x8
  bf16x8 B[16][3];
#pragma unroll
  for (int kc = 0; kc < 16; ++kc)
#pragma unroll
    for (int arr = 0; arr < 3; ++arr)
      B[kc][arr] = *(const bf16x8*)(
          Zf + ((size_t)(n32 * 3 + arr) * 16 + kc) * 512 + lane * 8);

  __syncthreads();   // publish ccs (only inter-wave data); sole barrier

// per-lane A fragment (g, kc, jx, arr): 16 B at lane*8 u16 within the
// 512-u16 frag cell — coalesced global_load_dwordx4, identical bytes to
// what r13 staged via LDS.
#define ALD(dst, gg, kcv, i_)                                                 \
  dst = *(const bf16x8*)(Cf +                                                 \
      (((size_t)(cg * 64 + (gg) * 2 + ((i_) / 3)) * 3 + ((i_) % 3)) * 16 +    \
       (kcv)) * 512 + lane * 8);

#define MF(af, bv, ac) ac = __builtin_amdgcn_mfma_f32_32x32x16_bf16(af, bv, ac, 0, 0, 0);
// bank layout: [i] = jx*3 + arr; a0[arr]=bank[arr], a1[arr]=bank[3+arr].
// Product order per acc element (a0b0,a0b1,a1b0,a1b1,a0b2,a2b0), kc
// ascending — bit-identical accumulation vs r3-r15.
#define MFSET(bk, kcv)                                                        \
  MF(bk[0], B[kcv][0], acc0) MF(bk[3], B[kcv][0], acc1)                       \
  MF(bk[0], B[kcv][1], acc0) MF(bk[3], B[kcv][1], acc1)                       \
  MF(bk[1], B[kcv][0], acc0) MF(bk[4], B[kcv][0], acc1)                       \
  MF(bk[1], B[kcv][1], acc0) MF(bk[4], B[kcv][1], acc1)                       \
  MF(bk[0], B[kcv][2], acc0) MF(bk[3], B[kcv][2], acc1)                       \
  MF(bk[2], B[kcv][0], acc0) MF(bk[5], B[kcv][0], acc1)

  float bd = INFINITY;
  int bj = 0;
  const f32x16 zero16 = {0,0,0,0,0,0,0,0,0,0,0,0,0,0,0,0};

  bf16x8 Ae[6], Ao[6];   // ping-pong banks (even kc / odd kc)

  // prologue: load (g=0, kc=0) into even bank
#pragma unroll
  for (int i = 0; i < 6; ++i) { ALD(Ae[i], 0, 0, i) }

  for (int g = 0; g < 32; ++g) {
    f32x16 acc0 = zero16, acc1 = zero16;
#pragma unroll
    for (int kc = 0; kc < 16; ++kc) {
      // prefetch phase P+1 into the other bank (clamped past the end —
      // dead loads, DCE-safe); then MFMA from the current bank.
      const int P = g * 16 + kc + 1;
      const int gn = (P >> 4) < 32 ? (P >> 4) : 0;
      const int kn = P & 15;
      if ((kc & 1) == 0) {
#pragma unroll
        for (int i = 0; i < 6; ++i) { ALD(Ao[i], gn, kn, i) }
        MFSET(Ae, kc)
      } else {
#pragma unroll
        for (int i = 0; i < 6; ++i) { ALD(Ae[i], gn, kn, i) }
        MFSET(Ao, kc)
      }
    }

    // epilogue: d = (zz + cc) - 2*acc, ascending j (same expression
    // r1-r15); overlaps the in-flight prefetch of the next group.
#pragma unroll
    for (int jx = 0; jx < 2; ++jx) {
      const f32x16& a = jx ? acc1 : acc0;
#pragma unroll
      for (int q = 0; q < 4; ++q) {
        const float4 c4 = *(const float4*)&ccs[g * 64 + jx * 32 + q * 8 + (lane >> 5) * 4];
        const float cv[4] = {c4.x, c4.y, c4.z, c4.w};
#pragma unroll
        for (int r = 0; r < 4; ++r) {
          const float d = (zzv + cv[r]) - 2.0f * a[q * 4 + r];
          const int j = cg * 2048 + g * 64 + jx * 32 + r + q * 8 + (lane >> 5) * 4;
          if (d < bd) { bd = d; bj = j; }
        }
      }
    }
  }
#undef ALD
#undef MF
#undef MFSET

  // combine lane halves (same z-row, complementary code sub-columns)
  {
    const float od = __shfl_xor(bd, 32);
    const int oj = __shfl_xor(bj, 32);
    if (od < bd || (od == bd && oj < bj)) { bd = od; bj = oj; }
  }
  if (lane < 32) {
    const int n = n32 * 32 + lane;
    pd[(size_t)cg * Nrows + n] = bd;
    pj[(size_t)cg * Nrows + n] = bj;
  }
}

// ---- fused combine + gather zq + loss (r13 structure, verified) -----------
// Grid 1024 = 256 row-tiles x 4 c-quarters; 17 KB LDS. All 4 cq blocks
// recompute the cheap 4-way argmin (identical comparison order -> bit-
// identical idx); only cq==0 publishes out_idx/counts. Stride-65 LDS rows:
// phase-3 banks (lane+c)%32 = 2-way (free).
__global__ __launch_bounds__(256) void vq_gather_loss(
    const float* __restrict__ z, const float* __restrict__ cb,
    const float* __restrict__ pd, const int* __restrict__ pj,
    float* __restrict__ outz, float* __restrict__ out_idxf,
    int* __restrict__ counts, float* __restrict__ loss_part) {
  __shared__ float cbl[64 * 65];    // 16.6 KB, stride 65
  __shared__ int jr[64];
  __shared__ float ws4[4];
  const int t = threadIdx.x;
  const int bid = blockIdx.x;       // 0..1023
  const int nt = bid >> 2;          // row tile 0..255
  const int cq = bid & 3;           // c-quarter 0..3
  const int b = nt >> 4;
  const int hw0 = (nt & 15) << 6;
  const int n0 = b * HWsz + hw0;

  // phase 1: combine NSPL partials (ascending s, lowest-j tie-break)
  if (t < 64) {
    const int n = n0 + t;
    float d0 = pd[n];
    int j0 = pj[n];
    for (int s = 1; s < NSPL; ++s) {
      const float d = pd[(size_t)s * Nrows + n];
      const int j = pj[(size_t)s * Nrows + n];
      if (d < d0 || (d == d0 && j < j0)) { d0 = d; j0 = j; }
    }
    jr[t] = j0;
    if (cq == 0) {
      out_idxf[n] = (float)j0;
      atomicAdd(&counts[j0], 1);
    }
  }
  __syncthreads();

  // phase 2: stage 64 rows x this block's 64-c slice (coalesced 256B rows)
  {
    const int r = t >> 2;
    const int c0 = (t & 3) * 16;
    const int j = jr[r];
    const float* src = cb + (size_t)j * Kdim + cq * 64 + c0;
#pragma unroll
    for (int q = 0; q < 4; ++q) {
      const float4 v = ((const float4*)src)[q];
      float* dst = &cbl[r * 65 + c0 + q * 4];
      dst[0] = v.x; dst[1] = v.y; dst[2] = v.z; dst[3] = v.w;
    }
  }
  __syncthreads();

  const int w = t >> 6, lane = t & 63;

  // phase 3: lane<->hw; wave w covers c_local = w*16 .. w*16+15
  float ls = 0.f;
  for (int k = 0; k < 16; ++k) {
    const int cl = w * 16 + k;
    const int c = cq * 64 + cl;
    const float q = cbl[lane * 65 + cl];
    const size_t gidx = ((size_t)(b * Kdim + c)) * HWsz + hw0 + lane;
    const float zv = z[gidx];
    outz[gidx] = q;
    const float dd = q - zv;
    ls = fmaf(dd, dd, ls);
  }
  for (int off = 32; off; off >>= 1) ls += __shfl_down(ls, off);
  if (lane == 0) ws4[w] = ls;
  __syncthreads();
  if (t == 0) loss_part[bid] = (ws4[0] + ws4[1]) + (ws4[2] + ws4[3]);
}

// ---- scalars: entropy + loss-partial reduction ----------------------------
__global__ __launch_bounds__(256) void vq_final(const int* __restrict__ counts,
                                                const float* __restrict__ loss_part,
                                                float* __restrict__ out_sc) {
  float h = 0.f;
  for (int i = threadIdx.x; i < NE; i += 256) {
    float p = (float)counts[i] * (1.0f / 16384.0f);
    h += p * logf(p + 1e-10f);
  }
  float ls = 0.f;
  for (int i = threadIdx.x; i < NGATHBLK; i += 256) ls += loss_part[i];
  for (int off = 32; off; off >>= 1) {
    h += __shfl_down(h, off);
    ls += __shfl_down(ls, off);
  }
  __shared__ float hs[4], lss[4];
  if ((threadIdx.x & 63) == 0) {
    hs[threadIdx.x >> 6] = h;
    lss[threadIdx.x >> 6] = ls;
  }
  __syncthreads();
  if (threadIdx.x == 0) {
    float H = (hs[0] + hs[1]) + (hs[2] + hs[3]);
    float L = (lss[0] + lss[1]) + (lss[2] + lss[3]);
    float m = L * (1.0f / 4194304.0f);
    out_sc[0] = m + BETAF * m;
    out_sc[1] = expf(-H);
  }
}

extern "C" void kernel_launch(void* const* d_in, const int* in_sizes, int n_in,
                              void* d_out, int out_size, void* d_ws, size_t ws_size,
                              hipStream_t stream) {
  const float* z = (const float*)d_in[0];
  const float* cb = (const float*)d_in[1];
  float* out = (float*)d_out;
  float* out_zq = out;                     // 4194304
  float* out_sc = out + 4194304;           // loss, perplexity
  float* out_idx = out + 4194306;          // 16384 idx as float

  char* wp = (char*)d_ws;
  u16* Cf = (u16*)wp;           wp += (size_t)NE * Kdim * 2 * 3;
  u16* Zf = (u16*)wp;           wp += (size_t)Nrows * Kdim * 2 * 3;
  float* cc = (float*)wp;       wp += (size_t)NE * 4;
  float* zz = (float*)wp;       wp += (size_t)Nrows * 4;
  float* pd = (float*)wp;       wp += (size_t)NSPL * Nrows * 4;
  int* pj = (int*)wp;           wp += (size_t)NSPL * Nrows * 4;
  int* counts = (int*)wp;       wp += (size_t)NE * 4;
  float* loss_part = (float*)wp; wp += (size_t)NGATHBLK * 4;

  hipMemsetAsync(counts, 0, (size_t)NE * 4, stream);

  cc_kernel<<<NE / 4, 256, 0, stream>>>(cb, cc);
  conv_cb<<<NE * 16 / 256, 256, 0, stream>>>(cb, Cf);
  conv_z<<<Nrows / 64, 256, 0, stream>>>(z, Zf, zz);
  vq_gemm<<<512, 256, 0, stream>>>(Cf, Zf, cc, zz, pd, pj);
  vq_gather_loss<<<NGATHBLK, 256, 0, stream>>>(z, cb, pd, pj, out_zq, out_idx,
                                               counts, loss_part);
  vq_final<<<1, 256, 0, stream>>>(counts, loss_part, out_sc);
}

// Round 12
// 409.787 us; speedup vs baseline: 1.4362x; 1.4362x over previous
//
#include <hip/hip_runtime.h>
#include <math.h>

#define Nrows 16384          // B*H*W
#define NE 8192
#define Kdim 256
#define HWsz 1024
#define NSPL 4               // code-group splits (cg)
#define BETAF 0.25f
#define NGATHBLK 1024        // gather grid: 256 row-tiles x 4 c-quarters

typedef __attribute__((ext_vector_type(8))) short bf16x8;
typedef __attribute__((ext_vector_type(16))) float f32x16;
typedef unsigned short u16;

__device__ inline u16 bf16_rne(float x) {
  unsigned int u = __float_as_uint(x);
  return (u16)((u + 0x7FFFu + ((u >> 16) & 1u)) >> 16);
}
__device__ inline float bf16_tof(u16 h) {
  return __uint_as_float(((unsigned int)h) << 16);
}
__device__ inline void gll16(const void* g, void* l) {
  __builtin_amdgcn_global_load_lds(
      (const __attribute__((address_space(1))) unsigned int*)g,
      (__attribute__((address_space(3))) unsigned int*)l, 16, 0, 0);
}

// ---- cc[j] = sum_k codebook[j][k]^2 (bit-identical to r1-r16) -------------
__global__ __launch_bounds__(256) void cc_kernel(const float* __restrict__ cb,
                                                 float* __restrict__ cc) {
  int wave = threadIdx.x >> 6;
  int lane = threadIdx.x & 63;
  int row = blockIdx.x * 4 + wave;
  const float4 v = *(const float4*)(cb + (size_t)row * Kdim + lane * 4);
  float s = v.x * v.x + v.y * v.y + v.z * v.z + v.w * v.w;
  for (int off = 32; off; off >>= 1) s += __shfl_down(s, off);
  if (lane == 0) cc[row] = s;
}

// ---- codebook -> frag-order bf16 splits Cf (unchanged r4-r16) -------------
// Group (j32, arr, k16) of 512 u16 at ((j32*3+arr)*16 + k16)*512;
// within group: (khalf*32 + j%32)*8 + i.
__global__ __launch_bounds__(256) void conv_cb(const float* __restrict__ cb,
                                               u16* __restrict__ Cf) {
  const int g = blockIdx.x * 256 + threadIdx.x;   // 0 .. 8192*16-1
  const int j = g >> 4, k16 = g & 15;
  const float* src = cb + (size_t)j * Kdim + k16 * 16;
  float f[16];
#pragma unroll
  for (int q = 0; q < 4; ++q) {
    const float4 v = ((const float4*)src)[q];
    f[q * 4 + 0] = v.x; f[q * 4 + 1] = v.y; f[q * 4 + 2] = v.z; f[q * 4 + 3] = v.w;
  }
  u16 h[3][16];
#pragma unroll
  for (int i = 0; i < 16; ++i) {
    const u16 q0 = bf16_rne(f[i]);
    const float r1 = f[i] - bf16_tof(q0);
    const u16 q1 = bf16_rne(r1);
    const float r2 = r1 - bf16_tof(q1);
    h[0][i] = q0; h[1][i] = q1; h[2][i] = bf16_rne(r2);
  }
  const int j32 = j >> 5, li = j & 31;
#pragma unroll
  for (int arr = 0; arr < 3; ++arr) {
#pragma unroll
    for (int kh = 0; kh < 2; ++kh) {
      const size_t off = ((size_t)(j32 * 3 + arr) * 16 + k16) * 512 + (kh * 32 + li) * 8;
      *(int4*)(Cf + off) = *(int4*)&h[arr][kh * 8];
    }
  }
}

// ---- z (B,C,H,W) -> frag-order bf16 splits Zf + zz ------------------------
// r17 change: the old `if(t<64)` serial zz loop (64 dependent fmaf iters on
// 1/4 of the threads, x4 kc, at 1 block/CU) is replaced by a per-thread
// 16-element partial over the SAME tile values the split conversion already
// reads, + quad __shfl_xor reduce (threads rr*4+0..3 are same-wave, quad-
// aligned). zz is ARGMIN-INVARIANT (uniform shift of all d's of a row; pd
// comparisons are within-row only), so the fp32 reorder cannot change idx,
// zq, counts, or loss. Zf path byte-identical.
__global__ __launch_bounds__(256) void conv_z(const float* __restrict__ z,
                                              u16* __restrict__ Zf,
                                              float* __restrict__ zz) {
  __shared__ float tile[64][68];
  const int t = threadIdx.x;
  const int bid = blockIdx.x;
  const int n0 = bid * 64;
  const int b = bid >> 4;
  const int hw0 = (bid & 15) << 6;
  const float* zb = z + (size_t)b * (Kdim * HWsz) + hw0;
  float zzacc = 0.f;
  const int rr = t >> 2;
  const int kq = (t & 3) * 16;
  for (int kc = 0; kc < 4; ++kc) {
#pragma unroll
    for (int i = 0; i < 16; ++i) {
      const int idx = i * 256 + t;
      const int k = idx >> 6, r = idx & 63;
      tile[r][k] = zb[(size_t)(kc * 64 + k) * HWsz + r];
    }
    __syncthreads();
    u16 h[3][16];
    float part = 0.f;
#pragma unroll
    for (int i = 0; i < 16; ++i) {
      const float fv = tile[rr][kq + i];
      part = fmaf(fv, fv, part);
      const u16 q0 = bf16_rne(fv);
      const float r1 = fv - bf16_tof(q0);
      const u16 q1 = bf16_rne(r1);
      const float r2 = r1 - bf16_tof(q1);
      h[0][i] = q0; h[1][i] = q1; h[2][i] = bf16_rne(r2);
    }
    // quad-reduce the 4 k-quarters of row rr (same wave, quad-aligned)
    part += __shfl_xor(part, 1);
    part += __shfl_xor(part, 2);
    zzacc += part;
    const int k16 = kc * 4 + (t & 3);
    const int n32 = bid * 2 + (rr >> 5), li = rr & 31;
#pragma unroll
    for (int arr = 0; arr < 3; ++arr) {
#pragma unroll
      for (int kh = 0; kh < 2; ++kh) {
        const size_t off = ((size_t)(n32 * 3 + arr) * 16 + k16) * 512 + (kh * 32 + li) * 8;
        *(int4*)(Zf + off) = *(int4*)&h[arr][kh * 8];
      }
    }
    __syncthreads();
  }
  if ((t & 3) == 0) zz[n0 + rr] = zzacc;
}

// ---- main GEMM+argmin: EXACT r13 (verified 326 us, MfmaUtil 62-64) --------
// 3-slot rotation, stage lag 2, counted vmcnt(6), raw s_barrier, 24 KB
// chunks, 4 barriers/group. r14 (4 blocks/CU) proved register-bound spill;
// r15 (per-wave pipelines) latency-bound; r16 (direct-to-reg) L1-BW-bound.
// This structure is the verified local optimum. MFMA order per acc element
// unchanged -> bit-identical. LDS 3x24KB + 8KB ccs = 80 KB -> 2 blocks/CU.
__global__ __launch_bounds__(256, 2) void vq_gemm(
    const u16* __restrict__ Cf, const u16* __restrict__ Zf,
    const float* __restrict__ cc, const float* __restrict__ zz,
    float* __restrict__ pd, int* __restrict__ pj) {
  __shared__ __align__(16) u16 Al[3][12288];   // 3 x 24 KB rotating slots
  __shared__ float ccs[2048];                  // 80 KB total

  const int t = threadIdx.x;
  const int lane = t & 63;
  const int w = __builtin_amdgcn_readfirstlane(t >> 6);   // 0..3
  const int bid = blockIdx.x;
  const int cg = bid & 3;          // code slice (2048 codes), XCD-pinned
  const int rt = bid >> 2;         // row tile (128 rows)
  const int n32 = rt * 4 + w;      // this wave's 32-row group

#pragma unroll
  for (int i = 0; i < 8; ++i) ccs[i * 256 + t] = cc[cg * 2048 + i * 256 + t];

  const float zzv = zz[n32 * 32 + (lane & 31)];

  // B (z-rows) persistent: 16 kc x 3 limbs x bf16x8 = 192 VGPRs
  bf16x8 B[16][3];
#pragma unroll
  for (int kc = 0; kc < 16; ++kc)
#pragma unroll
    for (int arr = 0; arr < 3; ++arr)
      B[kc][arr] = *(const bf16x8*)(
          Zf + ((size_t)(n32 * 3 + arr) * 16 + kc) * 512 + lane * 8);

// stage chunk (gg, c_) of 64-code group gg into LDS slot sl: 24 cells of
// 1 KB, 6 per wave; dest = wave-uniform cell base + lane*16 (gll16 rule).
// Tail over-issue clamps gg to 0 (valid, L2-hot, lands in a dead slot).
#define STAGE(gg, c_, sl)                                                     \
  {                                                                           \
    const int ggc_ = (gg) < 32 ? (gg) : 0;                                    \
    _Pragma("unroll")                                                         \
    for (int i = 0; i < 6; ++i) {                                             \
      const int s = w * 6 + i;                                                \
      const int jx = s / 12, rem = s % 12;                                    \
      const int kc2 = rem / 3, arr = rem % 3;                                 \
      gll16(Cf + ((size_t)((cg * 64 + ggc_ * 2 + jx) * 3 + arr) * 16 +        \
                  ((c_) * 4 + kc2)) * 512 + lane * 8,                         \
            &Al[sl][((jx * 4 + kc2) * 3 + arr) * 512]);                       \
    }                                                                         \
  }

// per kc: 6 A-frag b128 reads feed 12 MFMAs; per-acc-element product order
// (a0b0,a0b1,a1b0,a1b1,a0b2,a2b0) ascending kc — bit-identical to r3-r16.
#define MF(af, bv, ac) ac = __builtin_amdgcn_mfma_f32_32x32x16_bf16(af, bv, ac, 0, 0, 0);
#define CHUNK(sl, c_)                                                         \
  _Pragma("unroll")                                                           \
  for (int kc2 = 0; kc2 < 4; ++kc2) {                                         \
    bf16x8 a0[3], a1[3];                                                      \
    _Pragma("unroll")                                                         \
    for (int arr = 0; arr < 3; ++arr) {                                       \
      a0[arr] = *(const bf16x8*)&Al[sl][(kc2 * 3 + arr) * 512 + lane * 8];    \
      a1[arr] = *(const bf16x8*)&Al[sl][((4 + kc2) * 3 + arr) * 512 + lane * 8]; \
    }                                                                         \
    MF(a0[0], B[(c_) * 4 + kc2][0], acc0) MF(a1[0], B[(c_) * 4 + kc2][0], acc1) \
    MF(a0[0], B[(c_) * 4 + kc2][1], acc0) MF(a1[0], B[(c_) * 4 + kc2][1], acc1) \
    MF(a0[1], B[(c_) * 4 + kc2][0], acc0) MF(a1[1], B[(c_) * 4 + kc2][0], acc1) \
    MF(a0[1], B[(c_) * 4 + kc2][1], acc0) MF(a1[1], B[(c_) * 4 + kc2][1], acc1) \
    MF(a0[0], B[(c_) * 4 + kc2][2], acc0) MF(a1[0], B[(c_) * 4 + kc2][2], acc1) \
    MF(a0[2], B[(c_) * 4 + kc2][0], acc0) MF(a1[2], B[(c_) * 4 + kc2][0], acc1) \
  }

// counted wait + raw barrier: certifies the chunk about to be read (all
// waves), never drains the two younger in-flight stages. sched_barrier(0)
// fences stop compile-time motion of ds_reads/MFMAs across it (rule #18).
#define WTB()                                                                 \
  __builtin_amdgcn_sched_barrier(0);                                          \
  asm volatile("s_waitcnt vmcnt(6)" ::: "memory");                            \
  __builtin_amdgcn_s_barrier();                                               \
  __builtin_amdgcn_sched_barrier(0);

#define ROT() { sl = (sl == 2) ? 0 : sl + 1; s2 = (s2 == 2) ? 0 : s2 + 1; }

  // prologue: stage phases 0 and 1 into slots 0 and 1
  STAGE(0, 0, 0)
  STAGE(0, 1, 1)
  // publish ccs ds_writes before the first raw barrier (raw s_barrier does
  // not drain lgkmcnt the way __syncthreads did)
  asm volatile("s_waitcnt lgkmcnt(0)" ::: "memory");
  __builtin_amdgcn_sched_barrier(0);

  float bd = INFINITY;
  int bj = 0;
  const f32x16 zero16 = {0,0,0,0,0,0,0,0,0,0,0,0,0,0,0,0};
  int sl = 0, s2 = 2;   // slot of current phase / of phase+2 (uniform)

  for (int g = 0; g < 32; ++g) {
    f32x16 acc0 = zero16, acc1 = zero16;
    // 4 phases per group; stage runs 2 phases ahead: (g,2),(g,3),(g+1,0),(g+1,1)
    WTB() STAGE(g, 2, s2)     CHUNK(sl, 0) ROT()
    WTB() STAGE(g, 3, s2)     CHUNK(sl, 1) ROT()
    WTB() STAGE(g + 1, 0, s2) CHUNK(sl, 2) ROT()
    WTB() STAGE(g + 1, 1, s2) CHUNK(sl, 3) ROT()

    // epilogue: d = (zz + cc) - 2*acc, ascending j (same expression r1-r16);
    // overlaps the two in-flight stages of the next group.
#pragma unroll
    for (int jx = 0; jx < 2; ++jx) {
      const f32x16& a = jx ? acc1 : acc0;
#pragma unroll
      for (int q = 0; q < 4; ++q) {
        const float4 c4 = *(const float4*)&ccs[g * 64 + jx * 32 + q * 8 + (lane >> 5) * 4];
        const float cv[4] = {c4.x, c4.y, c4.z, c4.w};
#pragma unroll
        for (int r = 0; r < 4; ++r) {
          const float d = (zzv + cv[r]) - 2.0f * a[q * 4 + r];
          const int j = cg * 2048 + g * 64 + jx * 32 + r + q * 8 + (lane >> 5) * 4;
          if (d < bd) { bd = d; bj = j; }
        }
      }
    }
  }
  // drain clamped tail stages: no gll16 LDS-write may be pending at
  // s_endpgm (LDS is reallocated to the next workgroup).
  asm volatile("s_waitcnt vmcnt(0)" ::: "memory");
#undef STAGE
#undef CHUNK
#undef MF
#undef WTB
#undef ROT

  // combine lane halves (same z-row, complementary code sub-columns)
  {
    const float od = __shfl_xor(bd, 32);
    const int oj = __shfl_xor(bj, 32);
    if (od < bd || (od == bd && oj < bj)) { bd = od; bj = oj; }
  }
  if (lane < 32) {
    const int n = n32 * 32 + lane;
    pd[(size_t)cg * Nrows + n] = bd;
    pj[(size_t)cg * Nrows + n] = bj;
  }
}

// ---- fused combine + gather zq + loss (r13 structure, verified) -----------
// Grid 1024 = 256 row-tiles x 4 c-quarters; 17 KB LDS. All 4 cq blocks
// recompute the cheap 4-way argmin (identical comparison order -> bit-
// identical idx); only cq==0 publishes out_idx/counts. Stride-65 LDS rows:
// phase-3 banks (lane+c)%32 = 2-way (free).
__global__ __launch_bounds__(256) void vq_gather_loss(
    const float* __restrict__ z, const float* __restrict__ cb,
    const float* __restrict__ pd, const int* __restrict__ pj,
    float* __restrict__ outz, float* __restrict__ out_idxf,
    int* __restrict__ counts, float* __restrict__ loss_part) {
  __shared__ float cbl[64 * 65];    // 16.6 KB, stride 65
  __shared__ int jr[64];
  __shared__ float ws4[4];
  const int t = threadIdx.x;
  const int bid = blockIdx.x;       // 0..1023
  const int nt = bid >> 2;          // row tile 0..255
  const int cq = bid & 3;           // c-quarter 0..3
  const int b = nt >> 4;
  const int hw0 = (nt & 15) << 6;
  const int n0 = b * HWsz + hw0;

  // phase 1: combine NSPL partials (ascending s, lowest-j tie-break)
  if (t < 64) {
    const int n = n0 + t;
    float d0 = pd[n];
    int j0 = pj[n];
    for (int s = 1; s < NSPL; ++s) {
      const float d = pd[(size_t)s * Nrows + n];
      const int j = pj[(size_t)s * Nrows + n];
      if (d < d0 || (d == d0 && j < j0)) { d0 = d; j0 = j; }
    }
    jr[t] = j0;
    if (cq == 0) {
      out_idxf[n] = (float)j0;
      atomicAdd(&counts[j0], 1);
    }
  }
  __syncthreads();

  // phase 2: stage 64 rows x this block's 64-c slice (coalesced 256B rows)
  {
    const int r = t >> 2;
    const int c0 = (t & 3) * 16;
    const int j = jr[r];
    const float* src = cb + (size_t)j * Kdim + cq * 64 + c0;
#pragma unroll
    for (int q = 0; q < 4; ++q) {
      const float4 v = ((const float4*)src)[q];
      float* dst = &cbl[r * 65 + c0 + q * 4];
      dst[0] = v.x; dst[1] = v.y; dst[2] = v.z; dst[3] = v.w;
    }
  }
  __syncthreads();

  const int w = t >> 6, lane = t & 63;

  // phase 3: lane<->hw; wave w covers c_local = w*16 .. w*16+15
  float ls = 0.f;
  for (int k = 0; k < 16; ++k) {
    const int cl = w * 16 + k;
    const int c = cq * 64 + cl;
    const float q = cbl[lane * 65 + cl];
    const size_t gidx = ((size_t)(b * Kdim + c)) * HWsz + hw0 + lane;
    const float zv = z[gidx];
    outz[gidx] = q;
    const float dd = q - zv;
    ls = fmaf(dd, dd, ls);
  }
  for (int off = 32; off; off >>= 1) ls += __shfl_down(ls, off);
  if (lane == 0) ws4[w] = ls;
  __syncthreads();
  if (t == 0) loss_part[bid] = (ws4[0] + ws4[1]) + (ws4[2] + ws4[3]);
}

// ---- scalars: entropy + loss-partial reduction ----------------------------
__global__ __launch_bounds__(256) void vq_final(const int* __restrict__ counts,
                                                const float* __restrict__ loss_part,
                                                float* __restrict__ out_sc) {
  float h = 0.f;
  for (int i = threadIdx.x; i < NE; i += 256) {
    float p = (float)counts[i] * (1.0f / 16384.0f);
    h += p * logf(p + 1e-10f);
  }
  float ls = 0.f;
  for (int i = threadIdx.x; i < NGATHBLK; i += 256) ls += loss_part[i];
  for (int off = 32; off; off >>= 1) {
    h += __shfl_down(h, off);
    ls += __shfl_down(ls, off);
  }
  __shared__ float hs[4], lss[4];
  if ((threadIdx.x & 63) == 0) {
    hs[threadIdx.x >> 6] = h;
    lss[threadIdx.x >> 6] = ls;
  }
  __syncthreads();
  if (threadIdx.x == 0) {
    float H = (hs[0] + hs[1]) + (hs[2] + hs[3]);
    float L = (lss[0] + lss[1]) + (lss[2] + lss[3]);
    float m = L * (1.0f / 4194304.0f);
    out_sc[0] = m + BETAF * m;
    out_sc[1] = expf(-H);
  }
}

extern "C" void kernel_launch(void* const* d_in, const int* in_sizes, int n_in,
                              void* d_out, int out_size, void* d_ws, size_t ws_size,
                              hipStream_t stream) {
  const float* z = (const float*)d_in[0];
  const float* cb = (const float*)d_in[1];
  float* out = (float*)d_out;
  float* out_zq = out;                     // 4194304
  float* out_sc = out + 4194304;           // loss, perplexity
  float* out_idx = out + 4194306;          // 16384 idx as float

  char* wp = (char*)d_ws;
  u16* Cf = (u16*)wp;           wp += (size_t)NE * Kdim * 2 * 3;
  u16* Zf = (u16*)wp;           wp += (size_t)Nrows * Kdim * 2 * 3;
  float* cc = (float*)wp;       wp += (size_t)NE * 4;
  float* zz = (float*)wp;       wp += (size_t)Nrows * 4;
  float* pd = (float*)wp;       wp += (size_t)NSPL * Nrows * 4;
  int* pj = (int*)wp;           wp += (size_t)NSPL * Nrows * 4;
  int* counts = (int*)wp;       wp += (size_t)NE * 4;
  float* loss_part = (float*)wp; wp += (size_t)NGATHBLK * 4;

  hipMemsetAsync(counts, 0, (size_t)NE * 4, stream);

  cc_kernel<<<NE / 4, 256, 0, stream>>>(cb, cc);
  conv_cb<<<NE * 16 / 256, 256, 0, stream>>>(cb, Cf);
  conv_z<<<Nrows / 64, 256, 0, stream>>>(z, Zf, zz);
  vq_gemm<<<512, 256, 0, stream>>>(Cf, Zf, cc, zz, pd, pj);
  vq_gather_loss<<<NGATHBLK, 256, 0, stream>>>(z, cb, pd, pj, out_zq, out_idx,
                                               counts, loss_part);
  vq_final<<<1, 256, 0, stream>>>(counts, loss_part, out_sc);
}